// Round 5
// baseline (1349.256 us; speedup 1.0000x reference)
//
#include <hip/hip_runtime.h>

#define HID 512
#define G4 2048      // 4*HID
#define LSEQ 64
#define VOC 32000
#define EMBD 256
#define NBLK_L 64    // lstm blocks (one per 8 h-columns)
#define NTHR_L 1024  // lstm threads per block (16 waves: 8 k-ranges x 2 row-halves)
#define HSZ2 (HID * 32 * 2)   // floats per per-step {h,tag} buffer (128 KB)

using s16x8 = __attribute__((ext_vector_type(8))) short;   // 8 bf16 (4 VGPR)
using f32x4 = __attribute__((ext_vector_type(4))) float;   // MFMA acc frag

__device__ inline unsigned short f2bf_rn(float x) {
    unsigned u = __float_as_uint(x);
    unsigned r = (u + 0x7fffu + ((u >> 16) & 1u)) >> 16;
    return (unsigned short)r;
}
__device__ inline float bf2f(unsigned short h) {
    return __uint_as_float(((unsigned)h) << 16);
}
__device__ inline void gload_lds16(const void* g, void* l) {
    __builtin_amdgcn_global_load_lds(
        (const __attribute__((address_space(1))) void*)g,
        (__attribute__((address_space(3))) void*)l, 16, 0, 0);
}

// ---------------------------------------------------------------------------
// Kernel 1: input projection (encoder & decoder). Produces xwT layout:
// xwT[(t*2048 + g*512 + col)*32 + b]. 64x64 tile GEMM + LDS transpose.
// ---------------------------------------------------------------------------
__global__ __launch_bounds__(256) void input_proj_kernel(
    const int* __restrict__ Xtok, const int* __restrict__ Ytok,
    const float* __restrict__ embX, const float* __restrict__ embY,
    const float* __restrict__ WE, const float* __restrict__ WD,
    const float* __restrict__ bE, const float* __restrict__ bD,
    float* __restrict__ xwE, float* __restrict__ xwD)
{
    __shared__ float Al[32][68];
    __shared__ float Bl[32][68];
    __shared__ float Cl[64][68];
    const int tid = threadIdx.x;
    const int phase = blockIdx.z;
    const int* tokens = phase ? Ytok : Xtok;
    const float* emb  = phase ? embY : embX;
    const float* W    = phase ? WD : WE;
    const float* bv   = phase ? bD : bE;
    float* outp       = phase ? xwD : xwE;

    const int m0 = blockIdx.x * 64;
    const int n0 = blockIdx.y * 64;
    const int tm = tid & 15;
    const int tn = tid >> 4;

    float acc[4][4] = {};

    for (int kc = 0; kc < EMBD; kc += 32) {
#pragma unroll
        for (int r = 0; r < 2; ++r) {
            int i = tid + r * 256;
            int am = i >> 3;
            int kq = i & 7;
            int m = m0 + am;
            int t = m >> 5, b = m & 31;
            int tok;
            if (phase) { int tt = (t == 0) ? 0 : (t - 1); tok = tokens[b * LSEQ + tt]; }
            else       { tok = tokens[b * LSEQ + t]; }
            float4 av = *(const float4*)&emb[(size_t)tok * EMBD + kc + kq * 4];
            Al[kq * 4 + 0][am] = av.x; Al[kq * 4 + 1][am] = av.y;
            Al[kq * 4 + 2][am] = av.z; Al[kq * 4 + 3][am] = av.w;
            float4 wv = *(const float4*)&W[(size_t)(n0 + am) * EMBD + kc + kq * 4];
            Bl[kq * 4 + 0][am] = wv.x; Bl[kq * 4 + 1][am] = wv.y;
            Bl[kq * 4 + 2][am] = wv.z; Bl[kq * 4 + 3][am] = wv.w;
        }
        __syncthreads();
#pragma unroll
        for (int k = 0; k < 32; ++k) {
            float4 a  = *(const float4*)&Al[k][tm * 4];
            float4 b4 = *(const float4*)&Bl[k][tn * 4];
            acc[0][0] += a.x * b4.x; acc[0][1] += a.x * b4.y; acc[0][2] += a.x * b4.z; acc[0][3] += a.x * b4.w;
            acc[1][0] += a.y * b4.x; acc[1][1] += a.y * b4.y; acc[1][2] += a.y * b4.z; acc[1][3] += a.y * b4.w;
            acc[2][0] += a.z * b4.x; acc[2][1] += a.z * b4.y; acc[2][2] += a.z * b4.z; acc[2][3] += a.z * b4.w;
            acc[3][0] += a.w * b4.x; acc[3][1] += a.w * b4.y; acc[3][2] += a.w * b4.z; acc[3][3] += a.w * b4.w;
        }
        __syncthreads();
    }

    float4 bb = *(const float4*)&bv[n0 + tn * 4];
#pragma unroll
    for (int r = 0; r < 4; ++r) {
        Cl[tn * 4 + 0][tm * 4 + r] = acc[r][0] + bb.x;
        Cl[tn * 4 + 1][tm * 4 + r] = acc[r][1] + bb.y;
        Cl[tn * 4 + 2][tm * 4 + r] = acc[r][2] + bb.z;
        Cl[tn * 4 + 3][tm * 4 + r] = acc[r][3] + bb.w;
    }
    __syncthreads();

    const int t0 = m0 >> 5;
#pragma unroll
    for (int r = 0; r < 4; ++r) {
        int f = tid + r * 256;
        int nl = f >> 4;
        int rem = f & 15;
        int tp = rem >> 3;
        int bq = rem & 7;
        float4 v = *(const float4*)&Cl[nl][tp * 32 + bq * 4];
        *(float4*)&outp[((size_t)(t0 + tp) * G4 + n0 + nl) * 32 + bq * 4] = v;
    }
}

// ---------------------------------------------------------------------------
// Kernel 2: LSTM recurrence — 64 blocks x 1024 threads, self-publishing
// {h, tag} pairs. Block owns 8 h-cols (32 gate rows, lr = g*8+col).
// Wave w = (wk = w>>1 : k in [64wk,64wk+64), ws = w&1 : rows [16ws,16ws+16)).
// Wave loads+stages cols [64wk+32ws, +32) (sibling covers the other half),
// FMAs over its full 64-k range after a staging barrier. Partials reduced in
// two rounds through part[4][32][32]; 256 gate threads (tid<256: col=tid>>5,
// b=tid&31) hold cell state in registers, do gates, publish ONE relaxed
// AGENT 8B {h, tag s+1} store. 3 raw lgkmcnt+s_barrier per step, no vmcnt
// drains anywhere. Blocks >= NBLK_L do the fcW->bf16 hi/lo conversion
// concurrently (they never touch LDS or sync).
// ---------------------------------------------------------------------------
__global__ __launch_bounds__(1024, 4) void lstm_coop_kernel(
    const float* __restrict__ xwE, const float* __restrict__ xwD,
    const float* __restrict__ WhhE, const float* __restrict__ WhhD,
    float* __restrict__ H,
    const float* __restrict__ fcW, short* __restrict__ Bhi, short* __restrict__ Blo)
{
    __shared__ float WhhT[HID][32];      // 64 KB, [k][lr]
    __shared__ float htl[HID][32];       // 64 KB, [global col][b]
    __shared__ float part[4][32][32];    // 16 KB, two-round reduce

    const int tid = threadIdx.x;
    const int bid = blockIdx.x;

    if (bid >= NBLK_L) {                 // fused convW: fcW -> Bhi/Blo
        const size_t nchunk = (size_t)VOC * HID / 8;
        const size_t stride = (size_t)(gridDim.x - NBLK_L) * NTHR_L;
        for (size_t idx = (size_t)(bid - NBLK_L) * NTHR_L + tid; idx < nchunk;
             idx += stride) {
            size_t e0 = idx * 8;
            float4 v0 = *(const float4*)&fcW[e0];
            float4 v1 = *(const float4*)&fcW[e0 + 4];
            float xs[8] = {v0.x, v0.y, v0.z, v0.w, v1.x, v1.y, v1.z, v1.w};
            s16x8 h8, l8;
#pragma unroll
            for (int j = 0; j < 8; ++j) {
                unsigned short hi = f2bf_rn(xs[j]);
                h8[j] = (short)hi;
                l8[j] = (short)f2bf_rn(xs[j] - bf2f(hi));
            }
            *(s16x8*)&Bhi[e0] = h8;
            *(s16x8*)&Blo[e0] = l8;
        }
        return;
    }

    const int c0 = bid * 8;
    const int w = tid >> 6;
    const int wk = w >> 1;               // 0..7
    const int ws = w & 1;                // row half
    const int lane = tid & 63;
    const int rg = lane >> 4;            // 0..3
    const int bg = lane & 15;            // batch pair
    const int C0 = 64 * wk + 32 * ws;    // this wave's staging col range
    const int lr0 = 16 * ws + rg * 4;    // this lane's first local row
    const int gcol = tid >> 5;           // gate threads (tid<256)
    const int gb = tid & 31;
    float creg = 0.f;                    // cell state in register

    for (int s = 0; s < 2 * LSEQ; ++s) {
        const int phase = s >> 6;
        const int t = s & 63;
        if (t == 0) {
            const float* Whh = phase ? WhhD : WhhE;
            for (int idx = tid; idx < 32 * 128; idx += NTHR_L) {
                int lr = idx >> 7;       // 0..31
                int kq = idx & 127;
                int grow = (lr >> 3) * HID + c0 + (lr & 7);
                float4 v = *(const float4*)&Whh[(size_t)grow * HID + kq * 4];
                WhhT[kq * 4 + 0][lr] = v.x; WhhT[kq * 4 + 1][lr] = v.y;
                WhhT[kq * 4 + 2][lr] = v.z; WhhT[kq * 4 + 3][lr] = v.w;
            }
            __syncthreads();
        }

        // xw prefetch (h-independent, overlaps the poll)
        float xg0 = 0.f, xg1 = 0.f, xg2 = 0.f, xg3 = 0.f;
        if (tid < 256) {
            const float* xw = phase ? xwD : xwE;
            size_t xb = ((size_t)t * G4 + c0 + gcol) * 32 + gb;
            xg0 = xw[xb];
            xg1 = xw[xb + 1 * 512 * 32];
            xg2 = xw[xb + 2 * 512 * 32];
            xg3 = xw[xb + 3 * 512 * 32];
        }

        // batched retry-load of this wave's 32 cols x 32 b {h,tag} pairs
        const float* sp = H + (size_t)s * HSZ2;
        unsigned long long dv[16];
        for (;;) {
#pragma unroll
            for (int ii = 0; ii < 16; ++ii)
                dv[ii] = __hip_atomic_load(
                    (const unsigned long long*)(sp + ((size_t)C0 * 32 + ii * 64 + lane) * 2),
                    __ATOMIC_RELAXED, __HIP_MEMORY_SCOPE_AGENT);
            int ok = 1;
#pragma unroll
            for (int ii = 0; ii < 16; ++ii)
                ok &= ((int)(dv[ii] >> 32) == s);
            if (__all(ok)) break;
            __builtin_amdgcn_s_sleep(1);
        }
#pragma unroll
        for (int ii = 0; ii < 16; ++ii) {
            int p = ii * 64 + lane;
            htl[C0 + (p >> 5)][p & 31] = __uint_as_float((unsigned)dv[ii]);
        }
        asm volatile("s_waitcnt lgkmcnt(0)\ns_barrier" ::: "memory");  // B1: htl valid

        // FMA over this wave's full 64-k range, 4 rows x 2 batch per lane
        float acc[4][2] = {};
        const int k0 = 64 * wk;
#pragma unroll 8
        for (int k = k0; k < k0 + 64; ++k) {
            float4 wv = *(const float4*)&WhhT[k][lr0];
            float2 hv = *(const float2*)&htl[k][bg * 2];
            acc[0][0] += wv.x * hv.x; acc[0][1] += wv.x * hv.y;
            acc[1][0] += wv.y * hv.x; acc[1][1] += wv.y * hv.y;
            acc[2][0] += wv.z * hv.x; acc[2][1] += wv.z * hv.y;
            acc[3][0] += wv.w * hv.x; acc[3][1] += wv.w * hv.y;
        }

        // two-round partial reduce: wk<4 write, wk>=4 add
        if (wk < 4) {
#pragma unroll
            for (int ri = 0; ri < 4; ++ri)
                *(float2*)&part[wk][lr0 + ri][bg * 2] = make_float2(acc[ri][0], acc[ri][1]);
        }
        asm volatile("s_waitcnt lgkmcnt(0)\ns_barrier" ::: "memory");  // B2
        if (wk >= 4) {
#pragma unroll
            for (int ri = 0; ri < 4; ++ri) {
                float2 pv = *(float2*)&part[wk - 4][lr0 + ri][bg * 2];
                pv.x += acc[ri][0]; pv.y += acc[ri][1];
                *(float2*)&part[wk - 4][lr0 + ri][bg * 2] = pv;
            }
        }
        asm volatile("s_waitcnt lgkmcnt(0)\ns_barrier" ::: "memory");  // B3

        // gates + state update + publish (no end-of-step barrier needed:
        // next-step part writes are gated by B1, which gate waves join only
        // after their part reads retired)
        if (tid < 256) {
            float gi = xg0, gf = xg1, gg = xg2, go = xg3;
#pragma unroll
            for (int q = 0; q < 4; ++q) {
                gi += part[q][gcol][gb];
                gf += part[q][8 + gcol][gb];
                gg += part[q][16 + gcol][gb];
                go += part[q][24 + gcol][gb];
            }
            float si = 1.f / (1.f + __expf(-gi));
            float sf = 1.f / (1.f + __expf(-gf));
            float so = 1.f / (1.f + __expf(-go));
            float tg = tanhf(gg);
            float c = sf * creg + si * tg;
            creg = c;
            float h = so * tanhf(c);
            unsigned long long pv =
                ((unsigned long long)(unsigned)(s + 1) << 32) | __float_as_uint(h);
            __hip_atomic_store(
                (unsigned long long*)&H[(size_t)(s + 1) * HSZ2 + ((size_t)(c0 + gcol) * 32 + gb) * 2],
                pv, __ATOMIC_RELAXED, __HIP_MEMORY_SCOPE_AGENT);
        }
    }
}

// ---------------------------------------------------------------------------
// Kernel 4a (fallback path only): fcW (f32) -> Bhi/Blo (bf16).
// ---------------------------------------------------------------------------
__global__ __launch_bounds__(256) void convW_kernel(
    const float* __restrict__ W, short* __restrict__ Bhi, short* __restrict__ Blo)
{
    size_t idx = (size_t)blockIdx.x * 256 + threadIdx.x;
    size_t e0 = idx * 8;
    float4 v0 = *(const float4*)&W[e0];
    float4 v1 = *(const float4*)&W[e0 + 4];
    float xs[8] = {v0.x, v0.y, v0.z, v0.w, v1.x, v1.y, v1.z, v1.w};
    s16x8 h8, l8;
#pragma unroll
    for (int j = 0; j < 8; ++j) {
        unsigned short hi = f2bf_rn(xs[j]);
        h8[j] = (short)hi;
        l8[j] = (short)f2bf_rn(xs[j] - bf2f(hi));
    }
    *(s16x8*)&Bhi[e0] = h8;
    *(s16x8*)&Blo[e0] = l8;
}

// ---------------------------------------------------------------------------
// Kernel 4b: decoder H ({h,tag} pairs) -> Ahi/Alo bf16 [2048][512].
// ---------------------------------------------------------------------------
__global__ __launch_bounds__(256) void convA_kernel(
    const float* __restrict__ H65, short* __restrict__ Ahi, short* __restrict__ Alo)
{
    int idx = blockIdx.x * 256 + threadIdx.x;   // 131072 = 2048 m x 64 k8
    int m = idx & 2047;
    int k8 = idx >> 11;
    int t = m >> 5, b = m & 31;
    const float* Hs = H65 + (size_t)t * HSZ2;
    s16x8 h8, l8;
#pragma unroll
    for (int j = 0; j < 8; ++j) {
        int k = k8 * 8 + j;
        float x = Hs[(size_t)(k * 32 + b) * 2];
        unsigned short hi = f2bf_rn(x);
        h8[j] = (short)hi;
        l8[j] = (short)f2bf_rn(x - bf2f(hi));
    }
    *(s16x8*)&Ahi[(size_t)m * 512 + k8 * 8] = h8;
    *(s16x8*)&Alo[(size_t)m * 512 + k8 * 8] = l8;
}

// ---------------------------------------------------------------------------
// Kernel 5: FC via split-bf16 MFMA. C = Ahi*Bhi + Alo*Bhi + Ahi*Blo (+bias).
// 128x128 tile, 4 waves, K-step 64, global_load_lds(16), 16x16x32 bf16 MFMA.
// ---------------------------------------------------------------------------
__global__ __launch_bounds__(256) void fc_mfma_kernel(
    const short* __restrict__ Ahi, const short* __restrict__ Alo,
    const short* __restrict__ Bhi, const short* __restrict__ Blo,
    const float* __restrict__ bias, float* __restrict__ out)
{
    __shared__ short As[128 * 64];
    __shared__ short Bs[128 * 64];

    const int bi = blockIdx.x;
    const int wg = (bi & 7) * 500 + (bi >> 3);    // XCD-contiguous remap
    const int mt = wg & 15, nt = wg >> 4;
    const int m0 = mt * 128, n0 = nt * 128;
    const int tid = threadIdx.x;
    const int w = tid >> 6, lane = tid & 63;
    const int wm = w >> 1, wn = w & 1;
    const int srow = (lane >> 3);
    const int scol = (lane & 7) * 8;

    f32x4 acc[4][4] = {};

    for (int ks = 0; ks < 24; ++ks) {
        const int seg = ks >> 3;                  // 0: hi*hi 1: lo*hi 2: hi*lo
        const int kco = (ks & 7) * 64;
        const short* Asrc = (seg == 1) ? Alo : Ahi;
        const short* Bsrc = (seg == 2) ? Blo : Bhi;
#pragma unroll
        for (int i = 0; i < 4; ++i) {
            int row = w * 32 + i * 8 + srow;
            gload_lds16(&Asrc[(size_t)(m0 + row) * 512 + kco + scol],
                        (void*)&As[w * 2048 + i * 512]);
            gload_lds16(&Bsrc[(size_t)(n0 + row) * 512 + kco + scol],
                        (void*)&Bs[w * 2048 + i * 512]);
        }
        __syncthreads();

#pragma unroll
        for (int kk = 0; kk < 2; ++kk) {
            s16x8 af[4], bf[4];
#pragma unroll
            for (int f = 0; f < 4; ++f) {
                af[f] = *(const s16x8*)&As[(wm * 64 + f * 16 + (lane & 15)) * 64 + kk * 32 + (lane >> 4) * 8];
                bf[f] = *(const s16x8*)&Bs[(wn * 64 + f * 16 + (lane & 15)) * 64 + kk * 32 + (lane >> 4) * 8];
            }
#pragma unroll
            for (int fm = 0; fm < 4; ++fm)
#pragma unroll
                for (int fn = 0; fn < 4; ++fn)
                    acc[fm][fn] = __builtin_amdgcn_mfma_f32_16x16x32_bf16(
                        af[fm], bf[fn], acc[fm][fn], 0, 0, 0);
        }
        __syncthreads();
    }

    float bb[4];
#pragma unroll
    for (int fn = 0; fn < 4; ++fn)
        bb[fn] = bias[n0 + wn * 64 + fn * 16 + (lane & 15)];

#pragma unroll
    for (int fm = 0; fm < 4; ++fm) {
        int mbase = m0 + wm * 64 + fm * 16 + (lane >> 4) * 4;
#pragma unroll
        for (int r = 0; r < 4; ++r) {
            int m = mbase + r;
            int t = m >> 5, b = m & 31;
            float* orow = out + (size_t)(b * LSEQ + t) * VOC;
#pragma unroll
            for (int fn = 0; fn < 4; ++fn)
                orow[n0 + wn * 64 + fn * 16 + (lane & 15)] = acc[fm][fn][r] + bb[fn];
        }
    }
}

// ---------------------------------------------------------------------------
extern "C" void kernel_launch(void* const* d_in, const int* in_sizes, int n_in,
                              void* d_out, int out_size, void* d_ws, size_t ws_size,
                              hipStream_t stream)
{
    const int*   X    = (const int*)d_in[0];
    const int*   y    = (const int*)d_in[1];
    // d_in[2] = teacher_forcing (always 1, unused)
    const float* embX = (const float*)d_in[3];
    const float* WihE = (const float*)d_in[4];
    const float* WhhE = (const float*)d_in[5];
    const float* bE   = (const float*)d_in[6];
    const float* embY = (const float*)d_in[7];
    const float* WihD = (const float*)d_in[8];
    const float* WhhD = (const float*)d_in[9];
    const float* bD   = (const float*)d_in[10];
    const float* fcW  = (const float*)d_in[11];
    const float* fcB  = (const float*)d_in[12];
    float* out = (float*)d_out;

    char* ws = (char*)d_ws;
    const size_t XW_BYTES = (size_t)2048 * 2048 * 4;          // 16 MB each
    const size_t H_BYTES  = (size_t)129 * HSZ2 * 4;           // 16.9 MB
    const size_t A_BYTES  = (size_t)2048 * HID * 2;           // 2 MB each
    const size_t B_BYTES  = (size_t)VOC * HID * 2;            // 32 MB each

    const bool fuse = ws_size >= 2 * B_BYTES + 2 * XW_BYTES + H_BYTES + 2 * A_BYTES;
    float *xwE, *xwD, *H; short *Ahi, *Alo, *Bhi, *Blo;
    if (fuse) {
        // non-aliased layout: Bhi/Blo written concurrently with lstm
        Bhi = (short*)(ws);
        Blo = (short*)(ws + B_BYTES);
        xwE = (float*)(ws + 2 * B_BYTES);
        xwD = (float*)(ws + 2 * B_BYTES + XW_BYTES);
        H   = (float*)(ws + 2 * B_BYTES + 2 * XW_BYTES);
        Ahi = (short*)(ws + 2 * B_BYTES + 2 * XW_BYTES + H_BYTES);
        Alo = (short*)(ws + 2 * B_BYTES + 2 * XW_BYTES + H_BYTES + A_BYTES);
    } else {
        // R4 layout: Bhi aliases dead xw region, convW runs after lstm
        xwE = (float*)(ws);
        xwD = (float*)(ws + XW_BYTES);
        H   = (float*)(ws + 2 * XW_BYTES);
        Ahi = (short*)(ws + 2 * XW_BYTES + H_BYTES);
        Alo = (short*)(ws + 2 * XW_BYTES + H_BYTES + A_BYTES);
        Bhi = (short*)(ws);
        Blo = (short*)(ws + 2 * XW_BYTES + H_BYTES + 2 * A_BYTES);
    }

    // reset all H tags every launch (honest sync across graph replays);
    // H[0] = {h=0, tag=0} is the step-0 input.
    hipMemsetAsync((void*)H, 0, H_BYTES, stream);

    input_proj_kernel<<<dim3(32, 32, 2), 256, 0, stream>>>(
        X, y, embX, embY, WihE, WihD, bE, bD, xwE, xwD);

    {
        const float* a0 = xwE; const float* a1 = xwD;
        const float* a2 = WhhE; const float* a3 = WhhD;
        float* a4 = H;
        const float* a5 = fcW; short* a6 = Bhi; short* a7 = Blo;
        void* args[] = {&a0, &a1, &a2, &a3, &a4, &a5, &a6, &a7};
        hipLaunchCooperativeKernel((const void*)lstm_coop_kernel,
                                   dim3(fuse ? (NBLK_L + 160) : NBLK_L), dim3(NTHR_L),
                                   args, 0, stream);
    }

    if (!fuse)
        convW_kernel<<<8000, 256, 0, stream>>>(fcW, Bhi, Blo);

    convA_kernel<<<512, 256, 0, stream>>>(H + (size_t)65 * HSZ2, Ahi, Alo);

    fc_mfma_kernel<<<4000, 256, 0, stream>>>(Ahi, Alo, Bhi, Blo, fcB, out);
}